// Round 1
// baseline (99.551 us; speedup 1.0000x reference)
//
#include <hip/hip_runtime.h>
#include <math.h>

#define BB 4
#define LL 64
#define DD 64
#define NEG_ -1e9f

__device__ __forceinline__ float sigmoidf_(float x) { return 1.0f / (1.0f + expf(-x)); }

// w[b,i,k,e] = sum_d emb[x[b,i]][d] * rel[k][d*DD+e], for k=1..15 (k=0 is masked out downstream)
__global__ void rel_w_kernel(const int* __restrict__ x,
                             const float* __restrict__ emb,
                             const float* __restrict__ rel,
                             float* __restrict__ w)
{
    const int k = blockIdx.x + 1;   // 1..15
    const int i = blockIdx.y;
    const int b = blockIdx.z;
    const int t = threadIdx.x;
    __shared__ float o_i[DD];
    const int row = x[b * LL + i];
    o_i[t] = emb[row * DD + t];
    __syncthreads();
    const float* m = rel + k * DD * DD + t;   // column t, stride DD
    float a0 = 0.f, a1 = 0.f, a2 = 0.f, a3 = 0.f;
#pragma unroll
    for (int d = 0; d < DD; d += 4) {
        a0 = fmaf(o_i[d + 0], m[(d + 0) * DD], a0);
        a1 = fmaf(o_i[d + 1], m[(d + 1) * DD], a1);
        a2 = fmaf(o_i[d + 2], m[(d + 2) * DD], a2);
        a3 = fmaf(o_i[d + 3], m[(d + 3) * DD], a3);
    }
    w[((b * LL + i) * 16 + k) * DD + t] = (a0 + a1) + (a2 + a3);
}

// Per (b,i): scores -> softmax -> PV -> out-proj -> fused gx = o2@Wih.T + bih
__global__ void attn_kernel(const int* __restrict__ x, const int* __restrict__ r,
                            const float* __restrict__ emb, const float* __restrict__ w,
                            const float* __restrict__ aW, const float* __restrict__ ab,
                            const float* __restrict__ Wih, const float* __restrict__ bih,
                            float* __restrict__ gx)
{
    const int i = blockIdx.x, b = blockIdx.y, t = threadIdx.x;
    __shared__ float o_lds[LL][DD + 1];   // +1 pad: stride-64 reads hit all banks otherwise
    __shared__ float w_lds[16][DD + 1];
    __shared__ float p_lds[LL];
    __shared__ float ao_lds[DD];
    __shared__ float o2_lds[DD];

    for (int j = 0; j < LL; j++) o_lds[j][t] = emb[x[b * LL + j] * DD + t];
    for (int k = 1; k < 16; k++) w_lds[k][t] = w[((b * LL + i) * 16 + k) * DD + t];
    __syncthreads();

    const int rv = r[(b * LL + i) * LL + t];   // relation id for column j=t
    float s = NEG_;
    if (rv > 0) {
        float a0 = 0.f, a1 = 0.f;
#pragma unroll
        for (int e = 0; e < DD; e += 2) {
            a0 = fmaf(w_lds[rv][e + 0], o_lds[t][e + 0], a0);
            a1 = fmaf(w_lds[rv][e + 1], o_lds[t][e + 1], a1);
        }
        s = a0 + a1;
    }
    // wave(=block) softmax over j
    float mx = s;
    for (int off = 1; off < 64; off <<= 1) mx = fmaxf(mx, __shfl_xor(mx, off, 64));
    float ex = expf(s - mx);
    float sum = ex;
    for (int off = 1; off < 64; off <<= 1) sum += __shfl_xor(sum, off, 64);
    p_lds[t] = ex / sum;
    __syncthreads();

    float acc = 0.f;   // ao[d=t] = sum_j p[j]*o[j][t]
    for (int j = 0; j < LL; j++) acc = fmaf(p_lds[j], o_lds[j][t], acc);
    ao_lds[t] = acc;
    __syncthreads();

    float acc2 = ab[t];   // o2[d=t] = sum_e ao[e]*aW[t,e] + ab[t]
    const float* wr = aW + t * DD;
    for (int e = 0; e < DD; e++) acc2 = fmaf(ao_lds[e], wr[e], acc2);
    o2_lds[t] = acc2;
    __syncthreads();

#pragma unroll
    for (int m2 = 0; m2 < 3; m2++) {   // gx[g] = sum_e o2[e]*Wih[g,e] + bih[g]
        const int g = m2 * DD + t;
        float a = bih[g];
        const float* wg = Wih + g * DD;
        for (int e = 0; e < DD; e++) a = fmaf(o2_lds[e], wg[e], a);
        gx[(b * LL + i) * 192 + g] = a;
    }
}

// One block per batch: main GRU scan, output GRU (H=1), masked softmax pooling -> c
__global__ __launch_bounds__(192) void gru_kernel(
    const float* __restrict__ gx, const float* __restrict__ Whh, const float* __restrict__ bhh,
    const float* __restrict__ oWih, const float* __restrict__ oWhh,
    const float* __restrict__ obih, const float* __restrict__ obhh,
    const int* __restrict__ lvec, float* __restrict__ c_ws)
{
    const int b = blockIdx.x, g = threadIdx.x;
    __shared__ float h_lds[DD];
    __shared__ float gh_lds[192];
    __shared__ float o3[LL][DD + 1];
    __shared__ float gx2[LL][3];
    __shared__ float p2[LL];

    float wreg[DD];
#pragma unroll
    for (int e = 0; e < DD; e++) wreg[e] = Whh[g * DD + e];
    const float bg = bhh[g];
    if (g < DD) h_lds[g] = 0.0f;
    __syncthreads();

    for (int l = 0; l < LL; l++) {
        float a0 = 0.f, a1 = 0.f, a2 = 0.f, a3 = 0.f;
#pragma unroll
        for (int e = 0; e < DD; e += 4) {
            a0 = fmaf(h_lds[e + 0], wreg[e + 0], a0);
            a1 = fmaf(h_lds[e + 1], wreg[e + 1], a1);
            a2 = fmaf(h_lds[e + 2], wreg[e + 2], a2);
            a3 = fmaf(h_lds[e + 3], wreg[e + 3], a3);
        }
        gh_lds[g] = bg + ((a0 + a1) + (a2 + a3));
        __syncthreads();
        if (g < DD) {
            const float* gxl = gx + (b * LL + l) * 192;
            const float rg = sigmoidf_(gxl[g] + gh_lds[g]);
            const float zg = sigmoidf_(gxl[DD + g] + gh_lds[DD + g]);
            const float ng = tanhf(gxl[2 * DD + g] + rg * gh_lds[2 * DD + g]);
            const float hn = (1.0f - zg) * ng + zg * h_lds[g];
            h_lds[g] = hn;     // safe: all reads of h_lds finished before the barrier above
            o3[l][g] = hn;
        }
        __syncthreads();
    }

    // output-GRU input projections (parallel over l)
    if (g < LL) {
#pragma unroll
        for (int m = 0; m < 3; m++) {
            float a = obih[m];
            const float* wm = oWih + m * DD;
            for (int e = 0; e < DD; e++) a = fmaf(o3[g][e], wm[e], a);
            gx2[g][m] = a;
        }
    }
    __syncthreads();

    // H=1 scan (serial, thread 0)
    if (g == 0) {
        const float w0 = oWhh[0], w1 = oWhh[1], w2 = oWhh[2];
        const float c0 = obhh[0], c1 = obhh[1], c2 = obhh[2];
        float h = 0.0f;
        for (int l = 0; l < LL; l++) {
            const float rg = sigmoidf_(gx2[l][0] + h * w0 + c0);
            const float zg = sigmoidf_(gx2[l][1] + h * w1 + c1);
            const float ng = tanhf(gx2[l][2] + rg * (h * w2 + c2));
            h = (1.0f - zg) * ng + zg * h;
            p2[l] = h;
        }
    }
    __syncthreads();

    // bug-faithful mask: col <= max_b(l[b]); softmax on wave 0
    if (g < LL) {
        const int maxl = max(max(lvec[0], lvec[1]), max(lvec[2], lvec[3]));
        const float v = (g <= maxl) ? p2[g] : NEG_;
        float mx = v;
        for (int off = 1; off < 64; off <<= 1) mx = fmaxf(mx, __shfl_xor(mx, off, 64));
        const float ex = expf(v - mx);
        float sum = ex;
        for (int off = 1; off < 64; off <<= 1) sum += __shfl_xor(sum, off, 64);
        p2[g] = ex / sum;
    }
    __syncthreads();

    if (g < DD) {   // c[d] = sum_l p[l]*o3[l][d]
        float acc = 0.f;
        for (int l = 0; l < LL; l++) acc = fmaf(p2[l], o3[l][g], acc);
        c_ws[b * DD + g] = acc;
    }
}

// Classifier + softmax + loss for all batches; writes all 9 outputs
__global__ void cls_kernel(const float* __restrict__ c_ws, const int* __restrict__ y,
                           const float* __restrict__ W1, const float* __restrict__ b1,
                           const float* __restrict__ W2, const float* __restrict__ b2,
                           float* __restrict__ out)
{
    const int t = threadIdx.x;
    __shared__ float c_lds[DD];
    __shared__ float h1[32];
    __shared__ float lg[2];
    float loss = 0.0f;
    for (int b = 0; b < BB; b++) {
        c_lds[t] = c_ws[b * DD + t];
        __syncthreads();
        if (t < 32) {
            float a = b1[t];
            const float* wr = W1 + t * DD;
            for (int d = 0; d < DD; d++) a = fmaf(c_lds[d], wr[d], a);
            h1[t] = fmaxf(a, 0.0f);
        }
        __syncthreads();
        if (t < 2) {
            float a = b2[t];
            const float* wr = W2 + t * 32;
            for (int m2 = 0; m2 < 32; m2++) a = fmaf(h1[m2], wr[m2], a);
            lg[t] = a;
        }
        __syncthreads();
        if (t == 0) {
            const float l0 = lg[0], l1 = lg[1];
            const float mx = fmaxf(l0, l1);
            const float e0 = expf(l0 - mx), e1 = expf(l1 - mx);
            const float s = e0 + e1;
            out[b * 2 + 0] = e0 / s;
            out[b * 2 + 1] = e1 / s;
            const float lp = ((y[b] == 1) ? l1 : l0) - mx - logf(s);
            loss -= lp * 0.25f;
        }
        __syncthreads();
    }
    if (t == 0) out[8] = loss;
}

extern "C" void kernel_launch(void* const* d_in, const int* in_sizes, int n_in,
                              void* d_out, int out_size, void* d_ws, size_t ws_size,
                              hipStream_t stream)
{
    const int*   x    = (const int*)d_in[0];
    const int*   y    = (const int*)d_in[1];
    const int*   r    = (const int*)d_in[2];
    const int*   l    = (const int*)d_in[3];
    const float* emb  = (const float*)d_in[4];
    const float* rel  = (const float*)d_in[5];
    const float* aW   = (const float*)d_in[6];
    const float* ab   = (const float*)d_in[7];
    const float* Wih  = (const float*)d_in[8];
    const float* Whh  = (const float*)d_in[9];
    const float* bih  = (const float*)d_in[10];
    const float* bhh  = (const float*)d_in[11];
    const float* oWih = (const float*)d_in[12];
    const float* oWhh = (const float*)d_in[13];
    const float* obih = (const float*)d_in[14];
    const float* obhh = (const float*)d_in[15];
    const float* W1   = (const float*)d_in[16];
    const float* b1   = (const float*)d_in[17];
    const float* W2   = (const float*)d_in[18];
    const float* b2   = (const float*)d_in[19];

    float* ws  = (float*)d_ws;
    float* w   = ws;                       // B*L*16*D = 262144 floats
    float* gx  = ws + 262144;              // B*L*192  =  49152 floats
    float* cws = ws + 262144 + 49152;      // B*D      =    256 floats

    rel_w_kernel<<<dim3(15, LL, BB), DD, 0, stream>>>(x, emb, rel, w);
    attn_kernel<<<dim3(LL, BB), DD, 0, stream>>>(x, r, emb, w, aW, ab, Wih, bih, gx);
    gru_kernel<<<BB, 192, 0, stream>>>(gx, Whh, bhh, oWih, oWhh, obih, obhh, l, cws);
    cls_kernel<<<1, DD, 0, stream>>>(cws, y, W1, b1, W2, b2, (float*)d_out);
}

// Round 2
// 74.172 us; speedup vs baseline: 1.3422x; 1.3422x over previous
//
#include <hip/hip_runtime.h>
#include <math.h>

#define BB 4
#define LL 64
#define DD 64
#define NEG_ -1e9f

__device__ __forceinline__ float fast_sigmoid(float x) {
    return 1.0f / (1.0f + __expf(-x));
}
__device__ __forceinline__ float fast_tanh(float x) {
    x = fminf(15.0f, fmaxf(-15.0f, x));
    const float e = __expf(2.0f * x);
    return (e - 1.0f) / (e + 1.0f);
}

// w[b,i,k,e] = sum_d emb[x[b,i]][d] * rel[k][d*DD+e], for k=1..15 (k=0 masked downstream)
__global__ void rel_w_kernel(const int* __restrict__ x,
                             const float* __restrict__ emb,
                             const float* __restrict__ rel,
                             float* __restrict__ w)
{
    const int k = blockIdx.x + 1;   // 1..15
    const int i = blockIdx.y;
    const int b = blockIdx.z;
    const int t = threadIdx.x;
    __shared__ float o_i[DD];
    const int row = x[b * LL + i];
    o_i[t] = emb[row * DD + t];
    __syncthreads();
    const float* m = rel + k * DD * DD + t;   // column t, stride DD
    float a0 = 0.f, a1 = 0.f, a2 = 0.f, a3 = 0.f;
#pragma unroll
    for (int d = 0; d < DD; d += 4) {
        a0 = fmaf(o_i[d + 0], m[(d + 0) * DD], a0);
        a1 = fmaf(o_i[d + 1], m[(d + 1) * DD], a1);
        a2 = fmaf(o_i[d + 2], m[(d + 2) * DD], a2);
        a3 = fmaf(o_i[d + 3], m[(d + 3) * DD], a3);
    }
    w[((b * LL + i) * 16 + k) * DD + t] = (a0 + a1) + (a2 + a3);
}

// Per (b,i): scores -> softmax -> PV -> out-proj -> fused gx = o2@Wih.T + bih
__global__ void attn_kernel(const int* __restrict__ x, const int* __restrict__ r,
                            const float* __restrict__ emb, const float* __restrict__ w,
                            const float* __restrict__ aW, const float* __restrict__ ab,
                            const float* __restrict__ Wih, const float* __restrict__ bih,
                            float* __restrict__ gx)
{
    const int i = blockIdx.x, b = blockIdx.y, t = threadIdx.x;
    __shared__ float o_lds[LL][DD + 1];   // +1 pad: stride-64 reads hit all banks otherwise
    __shared__ float w_lds[16][DD + 1];
    __shared__ float p_lds[LL];
    __shared__ float ao_lds[DD];
    __shared__ float o2_lds[DD];

    for (int j = 0; j < LL; j++) o_lds[j][t] = emb[x[b * LL + j] * DD + t];
    for (int k = 1; k < 16; k++) w_lds[k][t] = w[((b * LL + i) * 16 + k) * DD + t];
    __syncthreads();

    const int rv = r[(b * LL + i) * LL + t];   // relation id for column j=t
    float s = NEG_;
    if (rv > 0) {
        float a0 = 0.f, a1 = 0.f;
#pragma unroll
        for (int e = 0; e < DD; e += 2) {
            a0 = fmaf(w_lds[rv][e + 0], o_lds[t][e + 0], a0);
            a1 = fmaf(w_lds[rv][e + 1], o_lds[t][e + 1], a1);
        }
        s = a0 + a1;
    }
    // wave(=block) softmax over j
    float mx = s;
    for (int off = 1; off < 64; off <<= 1) mx = fmaxf(mx, __shfl_xor(mx, off, 64));
    float ex = __expf(s - mx);
    float sum = ex;
    for (int off = 1; off < 64; off <<= 1) sum += __shfl_xor(sum, off, 64);
    p_lds[t] = ex / sum;
    __syncthreads();

    float acc = 0.f;   // ao[d=t] = sum_j p[j]*o[j][t]
    for (int j = 0; j < LL; j++) acc = fmaf(p_lds[j], o_lds[j][t], acc);
    ao_lds[t] = acc;
    __syncthreads();

    float acc2 = ab[t];   // o2[d=t] = sum_e ao[e]*aW[t,e] + ab[t]
    const float* wr = aW + t * DD;
    for (int e = 0; e < DD; e++) acc2 = fmaf(ao_lds[e], wr[e], acc2);
    o2_lds[t] = acc2;
    __syncthreads();

#pragma unroll
    for (int m2 = 0; m2 < 3; m2++) {   // gx[g] = sum_e o2[e]*Wih[g,e] + bih[g]
        const int g = m2 * DD + t;
        float a = bih[g];
        const float* wg = Wih + g * DD;
        for (int e = 0; e < DD; e++) a = fmaf(o2_lds[e], wg[e], a);
        gx[(b * LL + i) * 192 + g] = a;
    }
}

// One block per batch, 3 waves (192 threads).
// Key structure: gx fully staged in LDS; ONE barrier per scan step via
// double-buffered h/gh + redundant h-update in all 3 waves (identical values,
// so each wave's next-step read is ordered by its OWN write).
__global__ __launch_bounds__(192) void gru_kernel(
    const float* __restrict__ gx, const float* __restrict__ Whh, const float* __restrict__ bhh,
    const float* __restrict__ oWih, const float* __restrict__ oWhh,
    const float* __restrict__ obih, const float* __restrict__ obhh,
    const int* __restrict__ lvec, float* __restrict__ c_ws)
{
    const int b = blockIdx.x, g = threadIdx.x, t = g & 63;
    __shared__ float gx_lds[LL][192];      // 48 KB, no pad: flat float4 copy below
    __shared__ float h_lds[2][DD];
    __shared__ float gh_lds[2][192];
    __shared__ float o3[LL][DD + 1];
    __shared__ float gx2[LL][4];
    __shared__ float p2[LL];

    // bulk-stage gx (B-slice) into LDS: 3072 float4, flat, coalesced
    {
        const float4* src = (const float4*)(gx + b * LL * 192);
        float4* dst = (float4*)&gx_lds[0][0];
        for (int f = g; f < LL * 48; f += 192) dst[f] = src[f];
    }
    // per-thread Whh row in registers
    float wreg[DD];
    {
        const float4* wrow = (const float4*)(Whh + g * DD);
#pragma unroll
        for (int e = 0; e < 16; e++) {
            const float4 v = wrow[e];
            wreg[4 * e + 0] = v.x; wreg[4 * e + 1] = v.y;
            wreg[4 * e + 2] = v.z; wreg[4 * e + 3] = v.w;
        }
    }
    const float bg = bhh[g];
    if (g < DD) h_lds[0][g] = 0.0f;
    __syncthreads();

    int p = 0;
    for (int l = 0; l < LL; l++) {
        // phase 1: gh[g] = bhh[g] + h . Whh[g,:]  (broadcast b128 reads of h)
        float a0 = 0.f, a1 = 0.f, a2 = 0.f, a3 = 0.f;
#pragma unroll
        for (int e = 0; e < DD; e += 4) {
            const float4 hv = *(const float4*)&h_lds[p][e];
            a0 = fmaf(hv.x, wreg[e + 0], a0);
            a1 = fmaf(hv.y, wreg[e + 1], a1);
            a2 = fmaf(hv.z, wreg[e + 2], a2);
            a3 = fmaf(hv.w, wreg[e + 3], a3);
        }
        gh_lds[p][g] = bg + ((a0 + a1) + (a2 + a3));
        __syncthreads();   // the only barrier per step

        // phase 2: h-update, computed redundantly by all 3 waves (same values)
        const float hprev = h_lds[p][t];
        const float rg = fast_sigmoid(gx_lds[l][t] + gh_lds[p][t]);
        const float zg = fast_sigmoid(gx_lds[l][DD + t] + gh_lds[p][DD + t]);
        const float ng = fast_tanh(gx_lds[l][2 * DD + t] + rg * gh_lds[p][2 * DD + t]);
        const float hn = (1.0f - zg) * ng + zg * hprev;
        h_lds[p ^ 1][t] = hn;   // duplicate same-value writes across waves: benign
        o3[l][t] = hn;
        p ^= 1;
    }
    __syncthreads();

    // output-GRU input projections: 192 dots of length 64, one per thread
    {
        const int l = t, m = g >> 6;
        float a = obih[m];
        const float* wm = oWih + m * DD;
#pragma unroll
        for (int e = 0; e < DD; e += 4) {
            const float4 ov = *(const float4*)&o3[l][e];
            a = fmaf(ov.x, wm[e + 0], a);
            a = fmaf(ov.y, wm[e + 1], a);
            a = fmaf(ov.z, wm[e + 2], a);
            a = fmaf(ov.w, wm[e + 3], a);
        }
        gx2[l][m] = a;
    }
    __syncthreads();

    // H=1 scan (serial, thread 0)
    if (g == 0) {
        const float w0 = oWhh[0], w1 = oWhh[1], w2 = oWhh[2];
        const float c0 = obhh[0], c1 = obhh[1], c2 = obhh[2];
        float h = 0.0f;
        for (int l = 0; l < LL; l++) {
            const float rg = fast_sigmoid(gx2[l][0] + h * w0 + c0);
            const float zg = fast_sigmoid(gx2[l][1] + h * w1 + c1);
            const float ng = fast_tanh(gx2[l][2] + rg * (h * w2 + c2));
            h = (1.0f - zg) * ng + zg * h;
            p2[l] = h;
        }
    }
    __syncthreads();

    // bug-faithful mask: col <= max_b(l[b]); softmax on wave 0
    if (g < LL) {
        const int maxl = max(max(lvec[0], lvec[1]), max(lvec[2], lvec[3]));
        const float v = (g <= maxl) ? p2[g] : NEG_;
        float mx = v;
        for (int off = 1; off < 64; off <<= 1) mx = fmaxf(mx, __shfl_xor(mx, off, 64));
        const float ex = __expf(v - mx);
        float sum = ex;
        for (int off = 1; off < 64; off <<= 1) sum += __shfl_xor(sum, off, 64);
        p2[g] = ex / sum;
    }
    __syncthreads();

    if (g < DD) {   // c[d] = sum_l p[l]*o3[l][d]
        float acc = 0.f;
        for (int l = 0; l < LL; l++) acc = fmaf(p2[l], o3[l][g], acc);
        c_ws[b * DD + g] = acc;
    }
}

// Classifier + softmax + loss for all batches; writes all 9 outputs
__global__ void cls_kernel(const float* __restrict__ c_ws, const int* __restrict__ y,
                           const float* __restrict__ W1, const float* __restrict__ b1,
                           const float* __restrict__ W2, const float* __restrict__ b2,
                           float* __restrict__ out)
{
    const int t = threadIdx.x;
    __shared__ float c_lds[DD];
    __shared__ float h1[32];
    __shared__ float lg[2];
    float loss = 0.0f;
    for (int b = 0; b < BB; b++) {
        c_lds[t] = c_ws[b * DD + t];
        __syncthreads();
        if (t < 32) {
            float a = b1[t];
            const float* wr = W1 + t * DD;
            for (int d = 0; d < DD; d++) a = fmaf(c_lds[d], wr[d], a);
            h1[t] = fmaxf(a, 0.0f);
        }
        __syncthreads();
        if (t < 2) {
            float a = b2[t];
            const float* wr = W2 + t * 32;
            for (int m2 = 0; m2 < 32; m2++) a = fmaf(h1[m2], wr[m2], a);
            lg[t] = a;
        }
        __syncthreads();
        if (t == 0) {
            const float l0 = lg[0], l1 = lg[1];
            const float mx = fmaxf(l0, l1);
            const float e0 = __expf(l0 - mx), e1 = __expf(l1 - mx);
            const float s = e0 + e1;
            out[b * 2 + 0] = e0 / s;
            out[b * 2 + 1] = e1 / s;
            const float lp = ((y[b] == 1) ? l1 : l0) - mx - __logf(s);
            loss -= lp * 0.25f;
        }
        __syncthreads();
    }
    if (t == 0) out[8] = loss;
}

extern "C" void kernel_launch(void* const* d_in, const int* in_sizes, int n_in,
                              void* d_out, int out_size, void* d_ws, size_t ws_size,
                              hipStream_t stream)
{
    const int*   x    = (const int*)d_in[0];
    const int*   y    = (const int*)d_in[1];
    const int*   r    = (const int*)d_in[2];
    const int*   l    = (const int*)d_in[3];
    const float* emb  = (const float*)d_in[4];
    const float* rel  = (const float*)d_in[5];
    const float* aW   = (const float*)d_in[6];
    const float* ab   = (const float*)d_in[7];
    const float* Wih  = (const float*)d_in[8];
    const float* Whh  = (const float*)d_in[9];
    const float* bih  = (const float*)d_in[10];
    const float* bhh  = (const float*)d_in[11];
    const float* oWih = (const float*)d_in[12];
    const float* oWhh = (const float*)d_in[13];
    const float* obih = (const float*)d_in[14];
    const float* obhh = (const float*)d_in[15];
    const float* W1   = (const float*)d_in[16];
    const float* b1   = (const float*)d_in[17];
    const float* W2   = (const float*)d_in[18];
    const float* b2   = (const float*)d_in[19];

    float* ws  = (float*)d_ws;
    float* w   = ws;                       // B*L*16*D = 262144 floats
    float* gx  = ws + 262144;              // B*L*192  =  49152 floats
    float* cws = ws + 262144 + 49152;      // B*D      =    256 floats

    rel_w_kernel<<<dim3(15, LL, BB), DD, 0, stream>>>(x, emb, rel, w);
    attn_kernel<<<dim3(LL, BB), DD, 0, stream>>>(x, r, emb, w, aW, ab, Wih, bih, gx);
    gru_kernel<<<BB, 192, 0, stream>>>(gx, Whh, bhh, oWih, oWhh, obih, obhh, l, cws);
    cls_kernel<<<1, DD, 0, stream>>>(cws, y, W1, b1, W2, b2, (float*)d_out);
}